// Round 1
// baseline (29030.890 us; speedup 1.0000x reference)
//
#include <hip/hip_runtime.h>
#include <stdint.h>
#include <stddef.h>

#define T_SEQ  512
#define NBATCH 64
#define EMBED  512
#define HIDDEN 1024
#define VOCAB  32000
#define NWG    128
#define NTHR   256

typedef __attribute__((ext_vector_type(8))) short short8;
typedef __attribute__((ext_vector_type(4))) float f32x4;

__device__ __forceinline__ unsigned short f2bf(float x) {
  union { float f; unsigned u; } v; v.f = x;
  unsigned r = v.u + 0x7FFFu + ((v.u >> 16) & 1u);   // round-to-nearest-even
  return (unsigned short)(r >> 16);
}
__device__ __forceinline__ float sigm(float x) { return 1.0f / (1.0f + __expf(-x)); }
__device__ __forceinline__ float tanh_(float x) {
  float e = __expf(2.0f * x);
  return 1.0f - 2.0f / (e + 1.0f);   // exact at +/-inf limits
}

// ---------------- embedding gather + bf16 cast: xs[t][b][e] ----------------
__global__ void embed_k(const int* __restrict__ texts, const float* __restrict__ emb,
                        unsigned short* __restrict__ xs) {
  const int bid = blockIdx.x;          // t*64 + b
  const int t = bid >> 6, b = bid & 63;
  const int row = texts[b * T_SEQ + t];
  const float* src = emb + (size_t)row * EMBED;
  const int e = threadIdx.x * 2;
  float2 v = *(const float2*)(src + e);
  unsigned pk = (unsigned)f2bf(v.x) | ((unsigned)f2bf(v.y) << 16);
  *(unsigned*)(xs + (size_t)bid * EMBED + e) = pk;
}

// ---------------- Wy f32 -> bf16 cast ----------------
__global__ void cast_wy_k(const float* __restrict__ wy, unsigned short* __restrict__ out) {
  const size_t total = (size_t)VOCAB * HIDDEN / 4;
  for (size_t i = (size_t)blockIdx.x * blockDim.x + threadIdx.x; i < total;
       i += (size_t)gridDim.x * blockDim.x) {
    f32x4 v = *(const f32x4*)(wy + i * 4);
    unsigned lo = (unsigned)f2bf(v[0]) | ((unsigned)f2bf(v[1]) << 16);
    unsigned hi = (unsigned)f2bf(v[2]) | ((unsigned)f2bf(v[3]) << 16);
    uint2 pk; pk.x = lo; pk.y = hi;
    *(uint2*)(out + i * 4) = pk;
  }
}

// ---------------- persistent 2-layer LSTM ----------------
// 128 WGs x 256 thr. WG w owns hidden dims [w*8, w*8+8) -> 32 gate rows
// [f d0-7 | i d0-7 | o d0-7 | c d0-7], weights bf16 in LDS (XOR-swizzled).
// Per step: 4 waves K-split GEMM (MFMA 16x16x32 bf16) -> LDS partial reduce ->
// f32 gate math -> write h (bf16) -> device-scope grid barrier.
__launch_bounds__(NTHR, 1)
__global__ void lstm_k(const unsigned short* __restrict__ xs,
                       unsigned short* __restrict__ hs0,
                       unsigned short* __restrict__ hT,       // [2][64][1024] bf16
                       unsigned* __restrict__ bar,            // [2]: counter, release
                       const float* __restrict__ Wf0, const float* __restrict__ Wi0,
                       const float* __restrict__ Wo0, const float* __restrict__ Wc0,
                       const float* __restrict__ bf0, const float* __restrict__ bi0,
                       const float* __restrict__ bo0, const float* __restrict__ bc0,
                       const float* __restrict__ Wf1, const float* __restrict__ Wi1,
                       const float* __restrict__ Wo1, const float* __restrict__ Wc1,
                       const float* __restrict__ bf1, const float* __restrict__ bi1,
                       const float* __restrict__ bo1, const float* __restrict__ bc1)
{
  __shared__ __align__(16) char smem[147456];   // 128K weights + 16K partials
  float* buf = (float*)(smem + 131072);
  const int tid  = threadIdx.x;
  const int w    = blockIdx.x;
  const int lane = tid & 63;
  const int wid  = tid >> 6;        // wave id = K-quarter
  const int ln   = lane & 15;
  const int qq   = lane >> 4;
  const int dme  = tid >> 5;        // this thread's hidden dim 0..7
  const int b0   = (tid & 31) * 2;  // this thread's batch pair
  const int gk   = w * 8 + dme;     // global hidden dim
  unsigned ep = 0;

  auto gbar = [&]() {               // device-scope grid barrier, monotonic epoch
    ++ep;
    __syncthreads();
    if (tid == 0) {
      __threadfence();
      unsigned a = __hip_atomic_fetch_add(bar, 1u, __ATOMIC_ACQ_REL,
                                          __HIP_MEMORY_SCOPE_AGENT) + 1u;
      if (a == (unsigned)NWG * ep)
        __hip_atomic_store(bar + 1, ep, __ATOMIC_RELEASE, __HIP_MEMORY_SCOPE_AGENT);
      while (__hip_atomic_load(bar + 1, __ATOMIC_ACQUIRE,
                               __HIP_MEMORY_SCOPE_AGENT) < ep) {
        __builtin_amdgcn_s_sleep(1);
      }
    }
    __syncthreads();
    __threadfence();
  };

  for (int layer = 0; layer < 2; ++layer) {
    const int XDIM = layer ? HIDDEN : EMBED;
    const int K    = HIDDEN + XDIM;          // 2048 / 1536
    const int ROWB = K * 2;
    const int KT   = K / 128;                // K-tiles per wave (16 / 12)
    const unsigned short* xsrc = layer ? hs0 : xs;
    const float* W0 = layer ? Wf1 : Wf0;
    const float* W1 = layer ? Wi1 : Wi0;
    const float* W2 = layer ? Wo1 : Wo0;
    const float* W3 = layer ? Wc1 : Wc0;
    const float* B0 = layer ? bf1 : bf0;
    const float* B1 = layer ? bi1 : bi0;
    const float* B2 = layer ? bo1 : bo0;
    const float* B3 = layer ? bc1 : bc0;

    // ---- stage this WG's 32 weight rows into LDS (bf16, swizzled) ----
    for (int g = 0; g < 4; ++g) {
      const float* Wsrc = (g == 0) ? W0 : (g == 1) ? W1 : (g == 2) ? W2 : W3;
      for (int d = 0; d < 8; ++d) {
        const int r = g * 8 + d;
        const float* src = Wsrc + (size_t)(w * 8 + d) * K;
        for (int k = tid * 4; k < K; k += NTHR * 4) {
          f32x4 v = *(const f32x4*)(src + k);
          unsigned lo = (unsigned)f2bf(v[0]) | ((unsigned)f2bf(v[1]) << 16);
          unsigned hi = (unsigned)f2bf(v[2]) | ((unsigned)f2bf(v[3]) << 16);
          int byte = r * ROWB + k * 2;
          byte ^= ((r & 7) << 4);
          uint2 pk; pk.x = lo; pk.y = hi;
          *(uint2*)(smem + byte) = pk;
        }
      }
    }
    // ---- zero h_in buffer (hT[0]) cooperatively: 32768 uints over 128 WGs ----
    ((unsigned*)hT)[w * NTHR + tid] = 0u;

    const float bsf = B0[gk], bsi = B1[gk], bso = B2[gk], bsc = B3[gk];
    float cst[2] = {0.0f, 0.0f};

    gbar();   // weights staged + h0 zeroed visible everywhere

    const int kbase = wid * (KT * 32);
    const int swz = (ln & 7) << 4;

    for (int t = 0; t < T_SEQ; ++t) {
      const unsigned short* hin  = hT + (size_t)(t & 1) * (NBATCH * HIDDEN);
      unsigned short*       hout = hT + (size_t)((t & 1) ^ 1) * (NBATCH * HIDDEN);
      const unsigned short* xrow = xsrc + (size_t)t * NBATCH * XDIM;

      f32x4 acc[2][4] = {};
      for (int kt = 0; kt < KT; ++kt) {
        const int k  = kbase + kt * 32;
        const int kk = k + qq * 8;
        short8 afrag[2];
        {
          int byte = ln * ROWB + kk * 2;
          afrag[0] = *(const short8*)(smem + (byte ^ swz));
          byte += 16 * ROWB;
          afrag[1] = *(const short8*)(smem + (byte ^ swz));
        }
        short8 bfrag[4];
        if (kk < HIDDEN) {
          #pragma unroll
          for (int nt = 0; nt < 4; ++nt)
            bfrag[nt] = *(const short8*)(hin + (size_t)(nt * 16 + ln) * HIDDEN + kk);
        } else {
          const int off2 = kk - HIDDEN;
          #pragma unroll
          for (int nt = 0; nt < 4; ++nt)
            bfrag[nt] = *(const short8*)(xrow + (size_t)(nt * 16 + ln) * XDIM + off2);
        }
        #pragma unroll
        for (int mt = 0; mt < 2; ++mt)
          #pragma unroll
          for (int nt = 0; nt < 4; ++nt)
            acc[mt][nt] = __builtin_amdgcn_mfma_f32_16x16x32_bf16(
                afrag[mt], bfrag[nt], acc[mt][nt], 0, 0, 0);
      }

      // ---- cross-wave K reduction through LDS ----
      if (wid < 2) {
        float* bb = buf + wid * 2048;
        #pragma unroll
        for (int mt = 0; mt < 2; ++mt)
          #pragma unroll
          for (int nt = 0; nt < 4; ++nt)
            #pragma unroll
            for (int j = 0; j < 4; ++j)
              bb[(mt * 16 + qq * 4 + j) * 64 + nt * 16 + ln] = acc[mt][nt][j];
      }
      __syncthreads();
      if (wid >= 2) {
        float* bb = buf + (wid - 2) * 2048;
        #pragma unroll
        for (int mt = 0; mt < 2; ++mt)
          #pragma unroll
          for (int nt = 0; nt < 4; ++nt)
            #pragma unroll
            for (int j = 0; j < 4; ++j) {
              const int idx = (mt * 16 + qq * 4 + j) * 64 + nt * 16 + ln;
              bb[idx] += acc[mt][nt][j];
            }
      }
      __syncthreads();

      // ---- f32 gate math for this thread's (dme, b0..b0+1) ----
      #pragma unroll
      for (int s = 0; s < 2; ++s) {
        const int b = b0 + s;
        const float gf = buf[dme * 64 + b]        + buf[2048 + dme * 64 + b]        + bsf;
        const float gi = buf[(8 + dme) * 64 + b]  + buf[2048 + (8 + dme) * 64 + b]  + bsi;
        const float go = buf[(16 + dme) * 64 + b] + buf[2048 + (16 + dme) * 64 + b] + bso;
        const float gc = buf[(24 + dme) * 64 + b] + buf[2048 + (24 + dme) * 64 + b] + bsc;
        const float ft = sigm(gf);
        const float it = sigm(gi);
        const float ot = sigm(go);
        const float ch = tanh_(gc);
        cst[s] = ft * cst[s] + it * ch;
        const float h = ot * tanh_(cst[s]);
        const unsigned short hb = f2bf(h);
        hout[(size_t)b * HIDDEN + gk] = hb;
        if (layer == 0) hs0[((size_t)t * NBATCH + b) * HIDDEN + gk] = hb;
      }
      gbar();
    }
  }
}

// ---------------- final projection: y[b][v] = h_last . Wy[v] + by[v] ----------------
__global__ void final_k(const unsigned short* __restrict__ wyb,    // [VOCAB][1024] bf16
                        const unsigned short* __restrict__ hlast,  // [64][1024] bf16
                        const float* __restrict__ by,
                        float* __restrict__ out)                   // [64][VOCAB] f32
{
  const int tid = threadIdx.x, lane = tid & 63, wid = tid >> 6;
  const int ln = lane & 15, qq = lane >> 4;
  const int vbase = (blockIdx.x * 4 + wid) * 16;
  f32x4 acc[4] = {};
  const unsigned short* arow = wyb + (size_t)(vbase + ln) * HIDDEN;
  for (int kt = 0; kt < 32; ++kt) {
    const int kk = kt * 32 + qq * 8;
    short8 a = *(const short8*)(arow + kk);
    #pragma unroll
    for (int nt = 0; nt < 4; ++nt) {
      short8 b = *(const short8*)(hlast + (size_t)(nt * 16 + ln) * HIDDEN + kk);
      acc[nt] = __builtin_amdgcn_mfma_f32_16x16x32_bf16(a, b, acc[nt], 0, 0, 0);
    }
  }
  const int v0 = vbase + qq * 4;
  const f32x4 bias = *(const f32x4*)(by + v0);
  #pragma unroll
  for (int nt = 0; nt < 4; ++nt) {
    const int b = nt * 16 + ln;
    f32x4 r = acc[nt] + bias;
    *(f32x4*)(out + (size_t)b * VOCAB + v0) = r;
  }
}

// ---------------- host ----------------
extern "C" void kernel_launch(void* const* d_in, const int* in_sizes, int n_in,
                              void* d_out, int out_size, void* d_ws, size_t ws_size,
                              hipStream_t stream) {
  (void)in_sizes; (void)n_in; (void)out_size; (void)ws_size;
  const int*   texts = (const int*)d_in[0];
  const float* emb   = (const float*)d_in[1];
  const float* Wf0 = (const float*)d_in[2];  const float* bf0 = (const float*)d_in[3];
  const float* Wi0 = (const float*)d_in[4];  const float* bi0 = (const float*)d_in[5];
  const float* Wo0 = (const float*)d_in[6];  const float* bo0 = (const float*)d_in[7];
  const float* Wc0 = (const float*)d_in[8];  const float* bc0 = (const float*)d_in[9];
  const float* Wf1 = (const float*)d_in[10]; const float* bf1 = (const float*)d_in[11];
  const float* Wi1 = (const float*)d_in[12]; const float* bi1 = (const float*)d_in[13];
  const float* Wo1 = (const float*)d_in[14]; const float* bo1 = (const float*)d_in[15];
  const float* Wc1 = (const float*)d_in[16]; const float* bc1 = (const float*)d_in[17];
  const float* Wy  = (const float*)d_in[18]; const float* by  = (const float*)d_in[19];

  char* ws = (char*)d_ws;
  // ws layout (bytes): [0] barrier(8B) | 4096 hT 2x64x1024 bf16 (262144)
  // | 266240 xs 512x64x512 bf16 (33554432) | 33820672 hs0 512x64x1024 bf16 (67108864)
  // | 100929536 Wy bf16 (65536000) | end 166465536
  unsigned*       bar = (unsigned*)ws;
  unsigned short* hT  = (unsigned short*)(ws + 4096);
  unsigned short* xs  = (unsigned short*)(ws + 266240);
  unsigned short* hs0 = (unsigned short*)(ws + 33820672);
  unsigned short* wyb = (unsigned short*)(ws + 100929536);
  float* out = (float*)d_out;

  hipMemsetAsync(bar, 0, 8, stream);   // reset barrier epochs every call
  embed_k<<<T_SEQ * NBATCH, 256, 0, stream>>>(texts, emb, xs);
  cast_wy_k<<<2048, 256, 0, stream>>>(Wy, wyb);
  lstm_k<<<NWG, NTHR, 0, stream>>>(xs, hs0, hT, bar,
                                   Wf0, Wi0, Wo0, Wc0, bf0, bi0, bo0, bc0,
                                   Wf1, Wi1, Wo1, Wc1, bf1, bi1, bo1, bc1);
  final_k<<<VOCAB / 64, 256, 0, stream>>>(wyb, hT, by, out);
}

// Round 2
// 13790.486 us; speedup vs baseline: 2.1051x; 2.1051x over previous
//
#include <hip/hip_runtime.h>
#include <stdint.h>
#include <stddef.h>

#define T_SEQ  512
#define NBATCH 64
#define EMBED  512
#define HIDDEN 1024
#define VOCAB  32000
#define NWG    128
#define NTHR   256
#define AGENT  __HIP_MEMORY_SCOPE_AGENT

#define RST   66                 // reduce-buffer row stride (floats): 4*66 % 32 = 8 banks
#define BUFH  (32 * RST)         // floats per K-half

typedef __attribute__((ext_vector_type(8))) short short8;
typedef __attribute__((ext_vector_type(4))) float f32x4;

__device__ __forceinline__ unsigned short f2bf(float x) {
  union { float f; unsigned u; } v; v.f = x;
  unsigned r = v.u + 0x7FFFu + ((v.u >> 16) & 1u);   // round-to-nearest-even
  return (unsigned short)(r >> 16);
}
__device__ __forceinline__ float sigm(float x) { return 1.0f / (1.0f + __expf(-x)); }
__device__ __forceinline__ float tanh_(float x) {
  float e = __expf(2.0f * x);
  return 1.0f - 2.0f / (e + 1.0f);
}

// ---------------- embedding gather + bf16 cast: xs[t][b][e] ----------------
__global__ void embed_k(const int* __restrict__ texts, const float* __restrict__ emb,
                        unsigned short* __restrict__ xs) {
  const int bid = blockIdx.x;          // t*64 + b
  const int t = bid >> 6, b = bid & 63;
  const int row = texts[b * T_SEQ + t];
  const float* src = emb + (size_t)row * EMBED;
  const int e = threadIdx.x * 2;
  float2 v = *(const float2*)(src + e);
  unsigned pk = (unsigned)f2bf(v.x) | ((unsigned)f2bf(v.y) << 16);
  *(unsigned*)(xs + (size_t)bid * EMBED + e) = pk;
}

// ---------------- Wy f32 -> bf16 cast ----------------
__global__ void cast_wy_k(const float* __restrict__ wy, unsigned short* __restrict__ out) {
  const size_t total = (size_t)VOCAB * HIDDEN / 4;
  for (size_t i = (size_t)blockIdx.x * blockDim.x + threadIdx.x; i < total;
       i += (size_t)gridDim.x * blockDim.x) {
    f32x4 v = *(const f32x4*)(wy + i * 4);
    unsigned lo = (unsigned)f2bf(v[0]) | ((unsigned)f2bf(v[1]) << 16);
    unsigned hi = (unsigned)f2bf(v[2]) | ((unsigned)f2bf(v[3]) << 16);
    uint2 pk; pk.x = lo; pk.y = hi;
    *(uint2*)(out + i * 4) = pk;
  }
}

// ---- tree grid barrier: relaxed atomics only (all shared data is sc1-stored).
// bar layout (uints, 128B-spaced): grp[g]=bar[g*32] g<8; root=bar[256]; rel=bar[288].
__device__ __forceinline__ void gbar_(unsigned* bar, unsigned ep, int tid, int w) {
  __syncthreads();                 // compiler drains vmcnt(0) per wave -> stores at MALL
  if (tid == 0) {
    unsigned old = __hip_atomic_fetch_add(bar + (w >> 4) * 32, 1u,
                                          __ATOMIC_RELAXED, AGENT);
    if (old == 16u * ep - 1u) {    // last arriver of my 16-WG group
      unsigned o2 = __hip_atomic_fetch_add(bar + 256, 1u, __ATOMIC_RELAXED, AGENT);
      if (o2 == 8u * ep - 1u)      // last group
        __hip_atomic_store(bar + 288, ep, __ATOMIC_RELAXED, AGENT);
    }
    while (__hip_atomic_load(bar + 288, __ATOMIC_RELAXED, AGENT) < ep)
      __builtin_amdgcn_s_sleep(1);
  }
  __syncthreads();
  // one inv per wave per step: subsequent cached reads of h pull fresh lines
  __builtin_amdgcn_fence(__ATOMIC_ACQUIRE, "agent");
}

// ---------------- one LSTM layer, persistent ----------------
template<int XDIM>
__device__ __forceinline__ void run_layer(
    const unsigned short* __restrict__ xsrc,   // [T][64][XDIM] bf16
    unsigned* __restrict__ hs0u,               // layer0 output store (u32 view), or null
    unsigned* __restrict__ hTu,                // [2][64][1024] bf16 as u32
    unsigned* __restrict__ bar, unsigned& ep,
    const float* __restrict__ W0, const float* __restrict__ W1,
    const float* __restrict__ W2, const float* __restrict__ W3,
    const float* __restrict__ B0, const float* __restrict__ B1,
    const float* __restrict__ B2, const float* __restrict__ B3,
    char* smem, float* buf, int w, int tid)
{
  constexpr int K    = HIDDEN + XDIM;          // 1536 / 2048
  constexpr int ROWB = K * 2;
  constexpr int KT   = K / 128;                // 12 / 16 K-tiles per wave
  const int lane = tid & 63;
  const int wid  = tid >> 6;                   // wave id = K-quarter
  const int ln   = lane & 15;
  const int qq   = lane >> 4;
  const int d0   = (tid & 3) * 2;              // this thread's dim pair (even)
  const int b    = tid >> 2;                   // this thread's batch 0..63
  const int gk0  = w * 8 + d0;

  // ---- stage this WG's 32 gate rows into LDS (bf16, XOR-swizzled) ----
  for (int g = 0; g < 4; ++g) {
    const float* Wsrc = (g == 0) ? W0 : (g == 1) ? W1 : (g == 2) ? W2 : W3;
    for (int d = 0; d < 8; ++d) {
      const int r = g * 8 + d;
      const float* src = Wsrc + (size_t)(w * 8 + d) * K;
      for (int k = tid * 4; k < K; k += NTHR * 4) {
        f32x4 v = *(const f32x4*)(src + k);
        unsigned lo = (unsigned)f2bf(v[0]) | ((unsigned)f2bf(v[1]) << 16);
        unsigned hi = (unsigned)f2bf(v[2]) | ((unsigned)f2bf(v[3]) << 16);
        int byte = r * ROWB + k * 2;
        byte ^= ((r & 7) << 4);
        uint2 pk; pk.x = lo; pk.y = hi;
        *(uint2*)(smem + byte) = pk;
      }
    }
  }
  // ---- zero both h ping-pong buffers with sc1 stores (visible at MALL) ----
  for (int i = w * NTHR + tid; i < NBATCH * HIDDEN; i += NWG * NTHR)
    __hip_atomic_store(hTu + i, 0u, __ATOMIC_RELAXED, AGENT);

  const float bsf0 = B0[gk0], bsf1 = B0[gk0 + 1];
  const float bsi0 = B1[gk0], bsi1 = B1[gk0 + 1];
  const float bso0 = B2[gk0], bso1 = B2[gk0 + 1];
  const float bsc0 = B3[gk0], bsc1 = B3[gk0 + 1];
  float c0 = 0.0f, c1 = 0.0f;

  gbar_(bar, ++ep, tid, w);      // weights staged + h0 zeroed, visible everywhere

  const int kbase = wid * (KT * 32);
  const int swz = (ln & 7) << 4;

  for (int t = 0; t < T_SEQ; ++t) {
    const unsigned short* hin =
        (const unsigned short*)hTu + (size_t)(t & 1) * (NBATCH * HIDDEN);
    unsigned* houtu = hTu + ((t & 1) ^ 1) * (NBATCH * HIDDEN / 2);
    const unsigned short* xrow = xsrc + (size_t)t * NBATCH * XDIM;

    f32x4 acc[2][4] = {};
    #pragma unroll 4
    for (int kt = 0; kt < KT; ++kt) {
      const int kk = kbase + kt * 32 + qq * 8;
      short8 afrag0, afrag1;
      {
        int byte = ln * ROWB + kk * 2;
        afrag0 = *(const short8*)(smem + (byte ^ swz));
        afrag1 = *(const short8*)(smem + ((byte + 16 * ROWB) ^ swz));
      }
      short8 bfrag[4];
      if (kk < HIDDEN) {
        #pragma unroll
        for (int nt = 0; nt < 4; ++nt)
          bfrag[nt] = *(const short8*)(hin + (size_t)(nt * 16 + ln) * HIDDEN + kk);
      } else {
        const int off2 = kk - HIDDEN;
        #pragma unroll
        for (int nt = 0; nt < 4; ++nt)
          bfrag[nt] = *(const short8*)(xrow + (size_t)(nt * 16 + ln) * XDIM + off2);
      }
      #pragma unroll
      for (int mt = 0; mt < 2; ++mt)
        #pragma unroll
        for (int nt = 0; nt < 4; ++nt)
          acc[mt][nt] = __builtin_amdgcn_mfma_f32_16x16x32_bf16(
              mt ? afrag1 : afrag0, bfrag[nt], acc[mt][nt], 0, 0, 0);
    }

    // ---- cross-wave K reduction through LDS (stride-66 rows: 2-way = free) ----
    if (wid < 2) {
      float* bb = buf + wid * BUFH;
      #pragma unroll
      for (int mt = 0; mt < 2; ++mt)
        #pragma unroll
        for (int nt = 0; nt < 4; ++nt)
          #pragma unroll
          for (int j = 0; j < 4; ++j)
            bb[(mt * 16 + qq * 4 + j) * RST + nt * 16 + ln] = acc[mt][nt][j];
    }
    __syncthreads();
    if (wid >= 2) {
      float* bb = buf + (wid - 2) * BUFH;
      #pragma unroll
      for (int mt = 0; mt < 2; ++mt)
        #pragma unroll
        for (int nt = 0; nt < 4; ++nt)
          #pragma unroll
          for (int j = 0; j < 4; ++j)
            bb[(mt * 16 + qq * 4 + j) * RST + nt * 16 + ln] += acc[mt][nt][j];
    }
    __syncthreads();

    // ---- f32 gate math: this thread owns dims (d0, d0+1) x batch b ----
    {
      const float gf0 = buf[(0  + d0) * RST + b] + buf[BUFH + (0  + d0) * RST + b] + bsf0;
      const float gf1 = buf[(1  + d0) * RST + b] + buf[BUFH + (1  + d0) * RST + b] + bsf1;
      const float gi0 = buf[(8  + d0) * RST + b] + buf[BUFH + (8  + d0) * RST + b] + bsi0;
      const float gi1 = buf[(9  + d0) * RST + b] + buf[BUFH + (9  + d0) * RST + b] + bsi1;
      const float go0 = buf[(16 + d0) * RST + b] + buf[BUFH + (16 + d0) * RST + b] + bso0;
      const float go1 = buf[(17 + d0) * RST + b] + buf[BUFH + (17 + d0) * RST + b] + bso1;
      const float gc0 = buf[(24 + d0) * RST + b] + buf[BUFH + (24 + d0) * RST + b] + bsc0;
      const float gc1 = buf[(25 + d0) * RST + b] + buf[BUFH + (25 + d0) * RST + b] + bsc1;
      c0 = sigm(gf0) * c0 + sigm(gi0) * tanh_(gc0);
      c1 = sigm(gf1) * c1 + sigm(gi1) * tanh_(gc1);
      const float h0 = sigm(go0) * tanh_(c0);
      const float h1 = sigm(go1) * tanh_(c1);
      const unsigned pk = (unsigned)f2bf(h0) | ((unsigned)f2bf(h1) << 16);
      const size_t oi = ((size_t)b * HIDDEN + gk0) >> 1;
      __hip_atomic_store(houtu + oi, pk, __ATOMIC_RELAXED, AGENT);
      if constexpr (XDIM == EMBED)   // layer 0: record full sequence for layer 1
        __hip_atomic_store(hs0u + ((((size_t)t * NBATCH + b) * HIDDEN + gk0) >> 1),
                           pk, __ATOMIC_RELAXED, AGENT);
    }
    gbar_(bar, ++ep, tid, w);
  }
}

__launch_bounds__(NTHR, 1)
__global__ void lstm_k(const unsigned short* __restrict__ xs,
                       unsigned short* __restrict__ hs0,
                       unsigned* __restrict__ hTu,
                       unsigned* __restrict__ bar,
                       const float* __restrict__ Wf0, const float* __restrict__ Wi0,
                       const float* __restrict__ Wo0, const float* __restrict__ Wc0,
                       const float* __restrict__ bf0, const float* __restrict__ bi0,
                       const float* __restrict__ bo0, const float* __restrict__ bc0,
                       const float* __restrict__ Wf1, const float* __restrict__ Wi1,
                       const float* __restrict__ Wo1, const float* __restrict__ Wc1,
                       const float* __restrict__ bf1, const float* __restrict__ bi1,
                       const float* __restrict__ bo1, const float* __restrict__ bc1)
{
  __shared__ __align__(16) char smem[131072 + 2 * BUFH * 4];
  float* buf = (float*)(smem + 131072);
  const int tid = threadIdx.x;
  const int w   = blockIdx.x;
  unsigned ep = 0;
  run_layer<EMBED>(xs, (unsigned*)hs0, hTu, bar, ep,
                   Wf0, Wi0, Wo0, Wc0, bf0, bi0, bo0, bc0, smem, buf, w, tid);
  run_layer<HIDDEN>(hs0, nullptr, hTu, bar, ep,
                    Wf1, Wi1, Wo1, Wc1, bf1, bi1, bo1, bc1, smem, buf, w, tid);
}

// ---------------- final projection: y[b][v] = h_last . Wy[v] + by[v] ----------------
__global__ void final_k(const unsigned short* __restrict__ wyb,    // [VOCAB][1024] bf16
                        const unsigned short* __restrict__ hlast,  // [64][1024] bf16
                        const float* __restrict__ by,
                        float* __restrict__ out)                   // [64][VOCAB] f32
{
  const int tid = threadIdx.x, lane = tid & 63, wid = tid >> 6;
  const int ln = lane & 15, qq = lane >> 4;
  const int vbase = (blockIdx.x * 4 + wid) * 16;
  f32x4 acc[4] = {};
  const unsigned short* arow = wyb + (size_t)(vbase + ln) * HIDDEN;
  for (int kt = 0; kt < 32; ++kt) {
    const int kk = kt * 32 + qq * 8;
    short8 a = *(const short8*)(arow + kk);
    #pragma unroll
    for (int nt = 0; nt < 4; ++nt) {
      short8 b = *(const short8*)(hlast + (size_t)(nt * 16 + ln) * HIDDEN + kk);
      acc[nt] = __builtin_amdgcn_mfma_f32_16x16x32_bf16(a, b, acc[nt], 0, 0, 0);
    }
  }
  const int v0 = vbase + qq * 4;
  const f32x4 bias = *(const f32x4*)(by + v0);
  #pragma unroll
  for (int nt = 0; nt < 4; ++nt) {
    const int b = nt * 16 + ln;
    f32x4 r = acc[nt] + bias;
    *(f32x4*)(out + (size_t)b * VOCAB + v0) = r;
  }
}

// ---------------- host ----------------
extern "C" void kernel_launch(void* const* d_in, const int* in_sizes, int n_in,
                              void* d_out, int out_size, void* d_ws, size_t ws_size,
                              hipStream_t stream) {
  (void)in_sizes; (void)n_in; (void)out_size; (void)ws_size;
  const int*   texts = (const int*)d_in[0];
  const float* emb   = (const float*)d_in[1];
  const float* Wf0 = (const float*)d_in[2];  const float* bf0 = (const float*)d_in[3];
  const float* Wi0 = (const float*)d_in[4];  const float* bi0 = (const float*)d_in[5];
  const float* Wo0 = (const float*)d_in[6];  const float* bo0 = (const float*)d_in[7];
  const float* Wc0 = (const float*)d_in[8];  const float* bc0 = (const float*)d_in[9];
  const float* Wf1 = (const float*)d_in[10]; const float* bf1 = (const float*)d_in[11];
  const float* Wi1 = (const float*)d_in[12]; const float* bi1 = (const float*)d_in[13];
  const float* Wo1 = (const float*)d_in[14]; const float* bo1 = (const float*)d_in[15];
  const float* Wc1 = (const float*)d_in[16]; const float* bc1 = (const float*)d_in[17];
  const float* Wy  = (const float*)d_in[18]; const float* by  = (const float*)d_in[19];

  char* ws = (char*)d_ws;
  // ws layout (bytes): [0] barrier (4KB) | 4096 hT 2x64x1024 bf16 (262144)
  // | 266240 xs 512x64x512 bf16 (33554432) | 33820672 hs0 512x64x1024 bf16 (67108864)
  // | 100929536 Wy bf16 (65536000) | end 166465536
  unsigned*       bar = (unsigned*)ws;
  unsigned*       hTu = (unsigned*)(ws + 4096);
  unsigned short* xs  = (unsigned short*)(ws + 266240);
  unsigned short* hs0 = (unsigned short*)(ws + 33820672);
  unsigned short* wyb = (unsigned short*)(ws + 100929536);
  float* out = (float*)d_out;

  hipMemsetAsync(bar, 0, 4096, stream);   // reset barrier counters every call
  embed_k<<<T_SEQ * NBATCH, 256, 0, stream>>>(texts, emb, xs);
  cast_wy_k<<<2048, 256, 0, stream>>>(Wy, wyb);
  lstm_k<<<NWG, NTHR, 0, stream>>>(xs, hs0, hTu, bar,
                                   Wf0, Wi0, Wo0, Wc0, bf0, bi0, bo0, bc0,
                                   Wf1, Wi1, Wo1, Wc1, bf1, bi1, bo1, bc1);
  final_k<<<VOCAB / 64, 256, 0, stream>>>(wyb, (const unsigned short*)hTu, by, out);
}

// Round 3
// 5152.488 us; speedup vs baseline: 5.6343x; 2.6765x over previous
//
#include <hip/hip_runtime.h>
#include <stdint.h>
#include <stddef.h>

#define T_SEQ  512
#define NBATCH 64
#define EMBED  512
#define HIDDEN 1024
#define VOCAB  32000
#define NWG    256
#define NTHR   256
#define AGENT  __HIP_MEMORY_SCOPE_AGENT
#define RING   260                       // state ring slots; reuse distance 259 steps
#define SLOT_E (NBATCH * 2048)           // bf16 elems per slot: [64][ h1(1024) | h0(1024) ]

#define RST   66                         // reduce-buffer row stride (floats)
#define BUFH  (32 * RST)

typedef __attribute__((ext_vector_type(8))) short short8;
typedef __attribute__((ext_vector_type(4))) float f32x4;

__device__ __forceinline__ unsigned short f2bf(float x) {
  union { float f; unsigned u; } v; v.f = x;
  unsigned r = v.u + 0x7FFFu + ((v.u >> 16) & 1u);   // round-to-nearest-even
  return (unsigned short)(r >> 16);
}
__device__ __forceinline__ float sigm(float x) { return 1.0f / (1.0f + __expf(-x)); }
__device__ __forceinline__ float tanh_(float x) {
  float e = __expf(2.0f * x);
  return 1.0f - 2.0f / (e + 1.0f);
}

// ---------------- embedding gather + bf16 cast: xs[t][b][e] ----------------
__global__ void embed_k(const int* __restrict__ texts, const float* __restrict__ emb,
                        unsigned short* __restrict__ xs) {
  const int bid = blockIdx.x;          // t*64 + b
  const int t = bid >> 6, b = bid & 63;
  const int row = texts[b * T_SEQ + t];
  const float* src = emb + (size_t)row * EMBED;
  const int e = threadIdx.x * 2;
  float2 v = *(const float2*)(src + e);
  unsigned pk = (unsigned)f2bf(v.x) | ((unsigned)f2bf(v.y) << 16);
  *(unsigned*)(xs + (size_t)bid * EMBED + e) = pk;
}

// ---- tree grid barrier (256 WGs = 16 groups x 16), relaxed agent atomics only.
// bar layout (uints): grp[g]=bar[g*32] g<16; root=bar[512]; rel=bar[544].
__device__ __forceinline__ void gbar_(unsigned* bar, unsigned ep, int tid, int g16) {
  __syncthreads();                 // drains each wave's vmcnt -> sc1 stores at MALL
  if (tid == 0) {
    unsigned old = __hip_atomic_fetch_add(bar + g16 * 32, 1u, __ATOMIC_RELAXED, AGENT);
    if (old == 16u * ep - 1u) {    // last arriver of my 16-WG group
      unsigned o2 = __hip_atomic_fetch_add(bar + 512, 1u, __ATOMIC_RELAXED, AGENT);
      if (o2 == 16u * ep - 1u)     // last group
        __hip_atomic_store(bar + 544, ep, __ATOMIC_RELAXED, AGENT);
    }
    while (__hip_atomic_load(bar + 544, __ATOMIC_RELAXED, AGENT) < ep)
      __builtin_amdgcn_s_sleep(1);
  }
  __syncthreads();
  // no L2 invalidation: all cross-step addresses are fresh (ring churn >> L2).
  __builtin_amdgcn_fence(__ATOMIC_ACQUIRE, "workgroup");  // compiler ordering only
  asm volatile("" ::: "memory");
}

// ---------------- one LSTM layer, persistent, weights in VGPRs ----------------
// State slot s layout: [64 batch][2048]: cols 0-1023 = h1(s-2), cols 1024-2047 = h0(s-1).
// Super-step s: L0 (LAG=0) computes t=s:  reads slot s hi + xs[t], writes slot s+1 hi.
//               L1 (LAG=1) computes t=s-1: reads slot s full,      writes slot s+1 lo.
template<int XDIM, int LAG>
__device__ __forceinline__ void run_layer(
    const unsigned short* __restrict__ xs_all,
    unsigned short* __restrict__ state,
    unsigned* __restrict__ bar,
    const float* __restrict__ W0, const float* __restrict__ W1,
    const float* __restrict__ W2, const float* __restrict__ W3,
    const float* __restrict__ B0, const float* __restrict__ B1,
    const float* __restrict__ B2, const float* __restrict__ B3,
    float* buf, int wl, int gw, int tid)
{
  constexpr int K  = HIDDEN + XDIM;      // 1536 / 2048
  constexpr int KT = K / 128;            // 12 / 16 K-tiles per wave (K-quarter)
  const int lane = tid & 63;
  const int wid  = tid >> 6;
  const int ln   = lane & 15;
  const int qq   = lane >> 4;
  const int d0   = (tid & 3) * 2;        // dim pair within WG's 8 dims
  const int b    = tid >> 2;             // batch 0..63
  const int gk0  = wl * 8 + d0;
  const int kbase = wid * (KT * 32);
  const int g16  = gw >> 4;
  unsigned ep = 0;

  // ---- stage this WG's 32 gate rows into VGPR fragments (one-time) ----
  short8 wreg[KT][2];
  #pragma unroll
  for (int m = 0; m < 2; ++m) {
    const int r = m * 16 + ln;           // LDS-row order: [f x8 | i x8 | o x8 | c x8]
    const int g = r >> 3;
    const float* Wp = (g == 0) ? W0 : (g == 1) ? W1 : (g == 2) ? W2 : W3;
    const float* row = Wp + (size_t)(wl * 8 + (r & 7)) * K;
    #pragma unroll
    for (int kt = 0; kt < KT; ++kt) {
      const int kk = kbase + kt * 32 + qq * 8;
      f32x4 lo = *(const f32x4*)(row + kk);
      f32x4 hi = *(const f32x4*)(row + kk + 4);
      short8 v;
      v[0] = (short)f2bf(lo[0]); v[1] = (short)f2bf(lo[1]);
      v[2] = (short)f2bf(lo[2]); v[3] = (short)f2bf(lo[3]);
      v[4] = (short)f2bf(hi[0]); v[5] = (short)f2bf(hi[1]);
      v[6] = (short)f2bf(hi[2]); v[7] = (short)f2bf(hi[3]);
      wreg[kt][m] = v;
    }
  }

  // ---- zero ring slots 0 and 1 (h0(-1), h1(-1) zeros), device-visible ----
  {
    unsigned* su = (unsigned*)state;
    const int idx = gw * NTHR + tid;                 // 0..65535 (= one slot in u32)
    __hip_atomic_store(su + idx, 0u, __ATOMIC_RELAXED, AGENT);
    __hip_atomic_store(su + 65536 + idx, 0u, __ATOMIC_RELAXED, AGENT);
  }

  const float bsf0 = B0[gk0], bsf1 = B0[gk0 + 1];
  const float bsi0 = B1[gk0], bsi1 = B1[gk0 + 1];
  const float bso0 = B2[gk0], bso1 = B2[gk0 + 1];
  const float bsc0 = B3[gk0], bsc1 = B3[gk0 + 1];
  float c0 = 0.0f, c1 = 0.0f;

  gbar_(bar, ++ep, tid, g16);            // weights + zero slots visible

  for (int s = 0; s <= T_SEQ; ++s) {
    const int t = s - LAG;
    if (t >= 0 && t < T_SEQ) {
      const int so  = s % RING;
      const int so1 = (s + 1) % RING;
      const unsigned short* slotS = state + (size_t)so * SLOT_E;
      const unsigned short* xrow = nullptr;
      if constexpr (XDIM == EMBED)
        xrow = xs_all + (size_t)t * (NBATCH * EMBED);

      f32x4 acc[2][4] = {};
      #pragma unroll
      for (int kt = 0; kt < KT; ++kt) {
        const int kk = kbase + kt * 32 + qq * 8;
        const unsigned short* src;
        int str, col;
        if constexpr (XDIM == HIDDEN) {      // L1: one contiguous [b][2048] row
          src = slotS; str = 2048; col = kk;
        } else {                             // L0: h0 = slot hi-half, x = xs
          const bool hid = (kbase + kt * 32) < HIDDEN;  // 32-tile never straddles
          src = hid ? (slotS + 1024) : xrow;
          str = hid ? 2048 : EMBED;
          col = hid ? kk : (kk - HIDDEN);
        }
        short8 bf[4];
        #pragma unroll
        for (int nt = 0; nt < 4; ++nt)
          bf[nt] = *(const short8*)(src + (size_t)(nt * 16 + ln) * str + col);
        #pragma unroll
        for (int mt = 0; mt < 2; ++mt)
          #pragma unroll
          for (int nt = 0; nt < 4; ++nt)
            acc[mt][nt] = __builtin_amdgcn_mfma_f32_16x16x32_bf16(
                wreg[kt][mt], bf[nt], acc[mt][nt], 0, 0, 0);
      }

      // ---- cross-wave K reduction through LDS ----
      if (wid < 2) {
        float* bb = buf + wid * BUFH;
        #pragma unroll
        for (int mt = 0; mt < 2; ++mt)
          #pragma unroll
          for (int nt = 0; nt < 4; ++nt)
            #pragma unroll
            for (int j = 0; j < 4; ++j)
              bb[(mt * 16 + qq * 4 + j) * RST + nt * 16 + ln] = acc[mt][nt][j];
      }
      __syncthreads();
      if (wid >= 2) {
        float* bb = buf + (wid - 2) * BUFH;
        #pragma unroll
        for (int mt = 0; mt < 2; ++mt)
          #pragma unroll
          for (int nt = 0; nt < 4; ++nt)
            #pragma unroll
            for (int j = 0; j < 4; ++j)
              bb[(mt * 16 + qq * 4 + j) * RST + nt * 16 + ln] += acc[mt][nt][j];
      }
      __syncthreads();

      // ---- f32 gate math: dims (gk0, gk0+1) x batch b ----
      {
        const float gf0 = buf[(0  + d0) * RST + b] + buf[BUFH + (0  + d0) * RST + b] + bsf0;
        const float gf1 = buf[(1  + d0) * RST + b] + buf[BUFH + (1  + d0) * RST + b] + bsf1;
        const float gi0 = buf[(8  + d0) * RST + b] + buf[BUFH + (8  + d0) * RST + b] + bsi0;
        const float gi1 = buf[(9  + d0) * RST + b] + buf[BUFH + (9  + d0) * RST + b] + bsi1;
        const float go0 = buf[(16 + d0) * RST + b] + buf[BUFH + (16 + d0) * RST + b] + bso0;
        const float go1 = buf[(17 + d0) * RST + b] + buf[BUFH + (17 + d0) * RST + b] + bso1;
        const float gc0 = buf[(24 + d0) * RST + b] + buf[BUFH + (24 + d0) * RST + b] + bsc0;
        const float gc1 = buf[(25 + d0) * RST + b] + buf[BUFH + (25 + d0) * RST + b] + bsc1;
        c0 = sigm(gf0) * c0 + sigm(gi0) * tanh_(gc0);
        c1 = sigm(gf1) * c1 + sigm(gi1) * tanh_(gc1);
        const float h0 = sigm(go0) * tanh_(c0);
        const float h1 = sigm(go1) * tanh_(c1);
        const unsigned pk = (unsigned)f2bf(h0) | ((unsigned)f2bf(h1) << 16);
        const size_t oe = (size_t)so1 * SLOT_E + (size_t)b * 2048
                        + (XDIM == EMBED ? 1024 : 0) + gk0;
        __hip_atomic_store((unsigned*)state + (oe >> 1), pk, __ATOMIC_RELAXED, AGENT);
      }
    }
    gbar_(bar, ++ep, tid, g16);
  }
}

__launch_bounds__(NTHR, 1)
__global__ void lstm_k(const unsigned short* __restrict__ xs,
                       unsigned short* __restrict__ state,
                       unsigned* __restrict__ bar,
                       const float* __restrict__ Wf0, const float* __restrict__ Wi0,
                       const float* __restrict__ Wo0, const float* __restrict__ Wc0,
                       const float* __restrict__ bf0, const float* __restrict__ bi0,
                       const float* __restrict__ bo0, const float* __restrict__ bc0,
                       const float* __restrict__ Wf1, const float* __restrict__ Wi1,
                       const float* __restrict__ Wo1, const float* __restrict__ Wc1,
                       const float* __restrict__ bf1, const float* __restrict__ bi1,
                       const float* __restrict__ bo1, const float* __restrict__ bc1)
{
  __shared__ __align__(16) float buf[2 * BUFH];
  const int tid = threadIdx.x;
  const int gw = blockIdx.x;
  if (gw < 128)
    run_layer<EMBED, 0>(xs, state, bar, Wf0, Wi0, Wo0, Wc0,
                        bf0, bi0, bo0, bc0, buf, gw, gw, tid);
  else
    run_layer<HIDDEN, 1>(nullptr, state, bar, Wf1, Wi1, Wo1, Wc1,
                         bf1, bi1, bo1, bc1, buf, gw - 128, gw, tid);
}

// ---------------- final projection: y[b][v] = h1(511) . Wy[v] + by[v] ----------------
__global__ void final_k(const float* __restrict__ Wy,                // [VOCAB][1024] f32
                        const unsigned short* __restrict__ hlast,    // [64][2048] lo-half
                        const float* __restrict__ by,
                        float* __restrict__ out)                     // [64][VOCAB] f32
{
  const int tid = threadIdx.x, lane = tid & 63, wid = tid >> 6;
  const int ln = lane & 15, qq = lane >> 4;
  const int vbase = (blockIdx.x * 4 + wid) * 16;
  f32x4 acc[4] = {};
  const float* arow = Wy + (size_t)(vbase + ln) * HIDDEN;
  for (int kt = 0; kt < 32; ++kt) {
    const int kk = kt * 32 + qq * 8;
    f32x4 lo = *(const f32x4*)(arow + kk);
    f32x4 hi = *(const f32x4*)(arow + kk + 4);
    short8 a;
    a[0] = (short)f2bf(lo[0]); a[1] = (short)f2bf(lo[1]);
    a[2] = (short)f2bf(lo[2]); a[3] = (short)f2bf(lo[3]);
    a[4] = (short)f2bf(hi[0]); a[5] = (short)f2bf(hi[1]);
    a[6] = (short)f2bf(hi[2]); a[7] = (short)f2bf(hi[3]);
    #pragma unroll
    for (int nt = 0; nt < 4; ++nt) {
      short8 bv = *(const short8*)(hlast + (size_t)(nt * 16 + ln) * 2048 + kk);
      acc[nt] = __builtin_amdgcn_mfma_f32_16x16x32_bf16(a, bv, acc[nt], 0, 0, 0);
    }
  }
  const int v0 = vbase + qq * 4;
  const f32x4 bias = *(const f32x4*)(by + v0);
  #pragma unroll
  for (int nt = 0; nt < 4; ++nt) {
    const int bb = nt * 16 + ln;
    f32x4 r = acc[nt] + bias;
    *(f32x4*)(out + (size_t)bb * VOCAB + v0) = r;
  }
}

// ---------------- host ----------------
extern "C" void kernel_launch(void* const* d_in, const int* in_sizes, int n_in,
                              void* d_out, int out_size, void* d_ws, size_t ws_size,
                              hipStream_t stream) {
  (void)in_sizes; (void)n_in; (void)out_size; (void)ws_size;
  const int*   texts = (const int*)d_in[0];
  const float* emb   = (const float*)d_in[1];
  const float* Wf0 = (const float*)d_in[2];  const float* bf0 = (const float*)d_in[3];
  const float* Wi0 = (const float*)d_in[4];  const float* bi0 = (const float*)d_in[5];
  const float* Wo0 = (const float*)d_in[6];  const float* bo0 = (const float*)d_in[7];
  const float* Wc0 = (const float*)d_in[8];  const float* bc0 = (const float*)d_in[9];
  const float* Wf1 = (const float*)d_in[10]; const float* bf1 = (const float*)d_in[11];
  const float* Wi1 = (const float*)d_in[12]; const float* bi1 = (const float*)d_in[13];
  const float* Wo1 = (const float*)d_in[14]; const float* bo1 = (const float*)d_in[15];
  const float* Wc1 = (const float*)d_in[16]; const float* bc1 = (const float*)d_in[17];
  const float* Wy  = (const float*)d_in[18]; const float* by  = (const float*)d_in[19];

  char* ws = (char*)d_ws;
  // ws layout (bytes): [0] barrier (4KB) | 4096 state ring 260x64x2048 bf16 (68,157,440)
  // | 68,161,536 xs 512x64x512 bf16 (33,554,432) | end 101,715,968
  unsigned*       bar   = (unsigned*)ws;
  unsigned short* state = (unsigned short*)(ws + 4096);
  unsigned short* xs    = (unsigned short*)(ws + 4096 + (size_t)RING * SLOT_E * 2);
  float* out = (float*)d_out;

  hipMemsetAsync(bar, 0, 4096, stream);   // reset barrier counters every call
  embed_k<<<T_SEQ * NBATCH, 256, 0, stream>>>(texts, emb, xs);
  lstm_k<<<NWG, NTHR, 0, stream>>>(xs, state, bar,
                                   Wf0, Wi0, Wo0, Wc0, bf0, bi0, bo0, bc0,
                                   Wf1, Wi1, Wo1, Wc1, bf1, bi1, bo1, bc1);
  // h1(511) lives in slot (T_SEQ+1)%RING = 253, cols 0-1023
  final_k<<<VOCAB / 64, 256, 0, stream>>>(
      Wy, state + (size_t)((T_SEQ + 1) % RING) * SLOT_E, by, out);
}